// Round 1
// baseline (514.833 us; speedup 1.0000x reference)
//
#include <hip/hip_runtime.h>

// exp(K) for K = skew(theta), 64x64, via scaling-and-squaring:
//   A = K * 2^-5  (||A|| <= 0.2 from Frobenius bound)
//   T8(A) by Paterson-Stockmeyer: A2, A3, then ((B2*A3)+B1)*A3 + B0
//   (B1, B0 reconstructed from materialized B2 so only 4 LDS buffers needed)
//   then 5 squarings. 9 matmuls/batch total vs reference's 22.
// fp32 throughout (no fp32 MFMA on CDNA4; bf16 would blow the threshold
// through the squaring chain). One 256-thread block per batch item.

#define Dm   64
#define LDm  68          // padded stride: breaks LDS bank conflicts, keeps 16B align
#define NTH  2016
#define BUFSZ (Dm * LDm)

// Taylor coefficients 1/k!
#define C6 1.3888888889e-3f
#define C7 1.9841269841e-4f
#define C8 2.4801587302e-5f
// B1 = D0*I + D1*A + D2*B2  (derived: A2 = (B2 - C6 I - C7 A)/C8)
#define D2 336.0f
#define D1 -0.025f
#define D0 -0.3f
// B0 = E0*I + E1*A + E2*B2
#define E2 20160.0f
#define E1 -3.0f
#define E0 -27.0f

__device__ __forceinline__ void mm64(const float* __restrict__ As,
                                     const float* __restrict__ Bs,
                                     float acc[4][4], int r0, int c0) {
#pragma unroll
    for (int i = 0; i < 4; ++i)
#pragma unroll
        for (int j = 0; j < 4; ++j) acc[i][j] = 0.0f;

#pragma unroll 2
    for (int k = 0; k < Dm; k += 4) {
        const float4 a0 = *reinterpret_cast<const float4*>(As + (r0 + 0) * LDm + k);
        const float4 a1 = *reinterpret_cast<const float4*>(As + (r0 + 1) * LDm + k);
        const float4 a2 = *reinterpret_cast<const float4*>(As + (r0 + 2) * LDm + k);
        const float4 a3 = *reinterpret_cast<const float4*>(As + (r0 + 3) * LDm + k);
        const float4 b0 = *reinterpret_cast<const float4*>(Bs + (k + 0) * LDm + c0);
        const float4 b1 = *reinterpret_cast<const float4*>(Bs + (k + 1) * LDm + c0);
        const float4 b2 = *reinterpret_cast<const float4*>(Bs + (k + 2) * LDm + c0);
        const float4 b3 = *reinterpret_cast<const float4*>(Bs + (k + 3) * LDm + c0);

#define STEPK(comp, bv)                                             \
        acc[0][0] = fmaf(a0.comp, bv.x, acc[0][0]);                 \
        acc[0][1] = fmaf(a0.comp, bv.y, acc[0][1]);                 \
        acc[0][2] = fmaf(a0.comp, bv.z, acc[0][2]);                 \
        acc[0][3] = fmaf(a0.comp, bv.w, acc[0][3]);                 \
        acc[1][0] = fmaf(a1.comp, bv.x, acc[1][0]);                 \
        acc[1][1] = fmaf(a1.comp, bv.y, acc[1][1]);                 \
        acc[1][2] = fmaf(a1.comp, bv.z, acc[1][2]);                 \
        acc[1][3] = fmaf(a1.comp, bv.w, acc[1][3]);                 \
        acc[2][0] = fmaf(a2.comp, bv.x, acc[2][0]);                 \
        acc[2][1] = fmaf(a2.comp, bv.y, acc[2][1]);                 \
        acc[2][2] = fmaf(a2.comp, bv.z, acc[2][2]);                 \
        acc[2][3] = fmaf(a2.comp, bv.w, acc[2][3]);                 \
        acc[3][0] = fmaf(a3.comp, bv.x, acc[3][0]);                 \
        acc[3][1] = fmaf(a3.comp, bv.y, acc[3][1]);                 \
        acc[3][2] = fmaf(a3.comp, bv.z, acc[3][2]);                 \
        acc[3][3] = fmaf(a3.comp, bv.w, acc[3][3]);

        STEPK(x, b0)
        STEPK(y, b1)
        STEPK(z, b2)
        STEPK(w, b3)
#undef STEPK
    }
}

__global__ __launch_bounds__(256, 2)
void so_expm_kernel(const float* __restrict__ theta, float* __restrict__ out, int nbatch) {
    __shared__ __align__(16) float sm[4 * BUFSZ];
    float* bA = sm;               // A, later R
    float* b2 = sm + BUFSZ;       // A2, then B2, then squaring ping-pong
    float* b3 = sm + 2 * BUFSZ;   // A3
    float* bT = sm + 3 * BUFSZ;   // Horner temp

    const int b   = blockIdx.x;
    const int tid = threadIdx.x;
    const int ty = tid >> 4, tx = tid & 15;
    const int r0 = ty * 4, c0 = tx * 4;
    if (b >= nbatch) return;

    // ---- build A = K * 2^-5 in LDS ----
    for (int idx = tid; idx < BUFSZ; idx += 256) bA[idx] = 0.0f;
    __syncthreads();

    const float scale = 1.0f / 32.0f;
    const float* th = theta + (size_t)b * NTH;
    for (int t = tid; t < NTH; t += 256) {
        // solve i: off(i) = i*(127-i)/2 <= t < off(i+1)
        int i = (int)((127.0f - sqrtf(16129.0f - 8.0f * (float)t)) * 0.5f);
        if (i < 0) i = 0;
        if (i > 62) i = 62;
        while (i * (127 - i) / 2 > t) --i;
        while ((i + 1) * (127 - (i + 1)) / 2 <= t) ++i;
        const int j = i + 1 + (t - i * (127 - i) / 2);
        const float v = th[t] * scale;
        bA[j * LDm + i] = v;    // lower triangle: +theta
        bA[i * LDm + j] = -v;   // upper triangle: -theta
    }
    __syncthreads();

    float acc[4][4];

#define STORE4(dst)                                                               \
    do {                                                                          \
        _Pragma("unroll")                                                         \
        for (int i = 0; i < 4; ++i) {                                             \
            float4 v = make_float4(acc[i][0], acc[i][1], acc[i][2], acc[i][3]);   \
            *reinterpret_cast<float4*>((dst) + (r0 + i) * LDm + c0) = v;          \
        }                                                                         \
    } while (0)

    // A2 = A*A
    mm64(bA, bA, acc, r0, c0);
    STORE4(b2);
    __syncthreads();

    // A3 = A2*A
    mm64(b2, bA, acc, r0, c0);
    STORE4(b3);
    __syncthreads();

    // b2 <- B2 = C8*A2 + C7*A + C6*I   (own-element RMW, race-free)
#pragma unroll
    for (int i = 0; i < 4; ++i)
#pragma unroll
        for (int j = 0; j < 4; ++j) {
            const int r = r0 + i, c = c0 + j;
            float v = C8 * b2[r * LDm + c] + C7 * bA[r * LDm + c] + ((r == c) ? C6 : 0.0f);
            b2[r * LDm + c] = v;
        }
    __syncthreads();

    // bT = B2*A3 + B1,  B1 = D0 I + D1 A + D2 B2
    mm64(b2, b3, acc, r0, c0);
#pragma unroll
    for (int i = 0; i < 4; ++i)
#pragma unroll
        for (int j = 0; j < 4; ++j) {
            const int r = r0 + i, c = c0 + j;
            acc[i][j] += ((r == c) ? D0 : 0.0f) + D1 * bA[r * LDm + c] + D2 * b2[r * LDm + c];
        }
    STORE4(bT);
    __syncthreads();

    // bA <- R = bT*A3 + B0,  B0 = E0 I + E1 A + E2 B2
    mm64(bT, b3, acc, r0, c0);
#pragma unroll
    for (int i = 0; i < 4; ++i)
#pragma unroll
        for (int j = 0; j < 4; ++j) {
            const int r = r0 + i, c = c0 + j;
            acc[i][j] += ((r == c) ? E0 : 0.0f) + E1 * bA[r * LDm + c] + E2 * b2[r * LDm + c];
        }
    __syncthreads();   // all epilogue reads of bA done before overwrite
    STORE4(bA);
    __syncthreads();

    // 5 squarings: bA -> b2 -> bA -> b2 -> bA -> (global)
    mm64(bA, bA, acc, r0, c0);
    STORE4(b2);
    __syncthreads();
    mm64(b2, b2, acc, r0, c0);
    STORE4(bA);
    __syncthreads();
    mm64(bA, bA, acc, r0, c0);
    STORE4(b2);
    __syncthreads();
    mm64(b2, b2, acc, r0, c0);
    STORE4(bA);
    __syncthreads();
    mm64(bA, bA, acc, r0, c0);

    // final squaring result -> global (fp32, coalesced float4)
    float* op = out + (size_t)b * (Dm * Dm);
#pragma unroll
    for (int i = 0; i < 4; ++i) {
        float4 v = make_float4(acc[i][0], acc[i][1], acc[i][2], acc[i][3]);
        *reinterpret_cast<float4*>(op + (r0 + i) * Dm + c0) = v;
    }
#undef STORE4
}

extern "C" void kernel_launch(void* const* d_in, const int* in_sizes, int n_in,
                              void* d_out, int out_size, void* d_ws, size_t ws_size,
                              hipStream_t stream) {
    const float* theta = (const float*)d_in[0];
    float* out = (float*)d_out;
    const int nbatch = in_sizes[0] / NTH;   // 8192
    so_expm_kernel<<<nbatch, 256, 0, stream>>>(theta, out, nbatch);
}

// Round 2
// 142.791 us; speedup vs baseline: 3.6055x; 3.6055x over previous
//
#include <hip/hip_runtime.h>

// exp(K), K = skew(theta) 64x64, via scaling-and-squaring with MFMA.
//   A = K * 2^-5 ; T6(A) by Paterson-Stockmeyer:
//     A2 = A*A, A3 = A2*A, P = I/6 + A/24 + A2/120 + A3/720,
//     T6 = I + A + A2/2 + P*A3 ; then 5 squarings (R^32 = exp(K)).
// A/A2/A3/P stored single-bf16 (entries ~3e-3, rounding harmless).
// R stored as split bf16 (hi+lo packed in u32) so each squaring is a
// 3-term MFMA product with ~2^-17 relative error; 2^5 amplification
// keeps total error ~4e-3 << 1.79e-2 threshold.
// Antisymmetry trick: A^T = -A, A3^T = -A3, so PS-phase B-operands are
// read from ROW planes with a result negation -> no col-planes needed
// until the squaring phase. One 256-thread block (4 waves, 2x2 wave
// grid, 32x32 tile/wave) per batch item. LDS 36 KB -> 4 blocks/CU.

typedef short s16x8 __attribute__((ext_vector_type(8)));
typedef float f32x4 __attribute__((ext_vector_type(4)));
typedef unsigned int u32;
typedef unsigned short u16;

#define NTH 2016
#define BF_STR 144      // bf16 plane row stride bytes (72 u16; odd 16B-slot stride -> conflict-free)
#define PK_STR 256      // packed u32 plane row stride bytes (64 u32)
#define OFF_A    0
#define OFF_A2   9216
#define OFF_A3   18432
#define OFF_P    27648
#define OFF_RROW 0      // overlays A/A2 after PS phase
#define OFF_RCOL 18432  // overlays A3/P after PS phase
#define LDS_BYTES 36864

__device__ __forceinline__ u32 bf16_rne(float x) {
    u32 u = __builtin_bit_cast(u32, x);
    return (u + 0x7FFFu + ((u >> 16) & 1u)) >> 16;
}
__device__ __forceinline__ float bf2f(u32 h) {
    return __builtin_bit_cast(float, h << 16);
}
__device__ __forceinline__ u32 pack_split(float x) {  // (lo16<<16)|hi16
    u32 hi = bf16_rne(x);
    float d = x - bf2f(hi);
    u32 lo = bf16_rne(d);
    return (lo << 16) | hi;
}
__device__ __forceinline__ s16x8 cast8(uint4 v) { return __builtin_bit_cast(s16x8, v); }

// 8 packed u32 (k-consecutive) -> hi-frag, lo-frag (8 bf16 each)
__device__ __forceinline__ void unpack2(uint4 p0, uint4 p1, s16x8& fh, s16x8& fl) {
    uint4 h, l;
    h.x = __builtin_amdgcn_perm(p0.y, p0.x, 0x05040100u);
    h.y = __builtin_amdgcn_perm(p0.w, p0.z, 0x05040100u);
    h.z = __builtin_amdgcn_perm(p1.y, p1.x, 0x05040100u);
    h.w = __builtin_amdgcn_perm(p1.w, p1.z, 0x05040100u);
    l.x = __builtin_amdgcn_perm(p0.y, p0.x, 0x07060302u);
    l.y = __builtin_amdgcn_perm(p0.w, p0.z, 0x07060302u);
    l.z = __builtin_amdgcn_perm(p1.y, p1.x, 0x07060302u);
    l.w = __builtin_amdgcn_perm(p1.w, p1.z, 0x07060302u);
    fh = cast8(h); fl = cast8(l);
}

__global__ __launch_bounds__(256, 4)
void so_expm_mfma(const float* __restrict__ theta, float* __restrict__ out, int nbatch) {
    __shared__ __align__(16) char sm[LDS_BYTES];
    const int tid = threadIdx.x;
    const int b   = blockIdx.x;
    const int l   = tid & 63;
    const int wid = tid >> 6;
    const int wr = wid >> 1, wc = wid & 1;   // 2x2 wave grid
    const int q = l & 15, g = l >> 4;        // MFMA lane decomposition

    // ---- zero A plane (2304 u32 = 9*256) ----
    {
        u32* z = reinterpret_cast<u32*>(sm + OFF_A);
        #pragma unroll
        for (int it = 0; it < 9; ++it) z[tid + it * 256] = 0u;
    }
    __syncthreads();

    // ---- scatter theta -> A = K * 2^-5 (bf16 row plane) ----
    {
        const float* th = theta + (size_t)b * NTH;
        u16* pa = reinterpret_cast<u16*>(sm + OFF_A);
        for (int t = tid; t < NTH; t += 256) {
            int i = (int)((127.0f - sqrtf(16129.0f - 8.0f * (float)t)) * 0.5f);
            if (i < 0) i = 0;
            if (i > 62) i = 62;
            while (i * (127 - i) / 2 > t) --i;
            while ((i + 1) * (127 - (i + 1)) / 2 <= t) ++i;
            const int j = i + 1 + (t - i * (127 - i) / 2);
            const float v = th[t] * 0.03125f;
            u32 hb = bf16_rne(v);
            pa[j * 72 + i] = (u16)hb;              // +theta (lower tri)
            pa[i * 72 + j] = (u16)(hb ^ 0x8000u);  // -theta (upper tri)
        }
    }
    __syncthreads();

    const f32x4 zf = {0.f, 0.f, 0.f, 0.f};

    // PS-phase matmul: acc[m][n] = sum_k L[m,k] * Brow[n,k]  (= L * B^T)
    auto mm_bf = [&](int aoff, int boff, f32x4 acc[2][2]) {
        #pragma unroll
        for (int ks = 0; ks < 2; ++ks) {
            s16x8 af[2], bfr[2];
            #pragma unroll
            for (int mt = 0; mt < 2; ++mt)
                af[mt] = cast8(*reinterpret_cast<const uint4*>(
                    sm + aoff + (32 * wr + 16 * mt + q) * BF_STR + 64 * ks + 16 * g));
            #pragma unroll
            for (int nt = 0; nt < 2; ++nt)
                bfr[nt] = cast8(*reinterpret_cast<const uint4*>(
                    sm + boff + (32 * wc + 16 * nt + q) * BF_STR + 64 * ks + 16 * g));
            #pragma unroll
            for (int mt = 0; mt < 2; ++mt)
                #pragma unroll
                for (int nt = 0; nt < 2; ++nt)
                    acc[mt][nt] = __builtin_amdgcn_mfma_f32_16x16x32_bf16(
                        af[mt], bfr[nt], acc[mt][nt], 0, 0, 0);
        }
    };

    // squaring matmul: acc = R*R from split packed planes (3-term split)
    auto mm_sq = [&](f32x4 acc[2][2]) {
        #pragma unroll
        for (int ks = 0; ks < 2; ++ks) {
            s16x8 ah[2], al[2], bh[2], bl[2];
            #pragma unroll
            for (int mt = 0; mt < 2; ++mt) {
                int r = 32 * wr + 16 * mt + q;
                int base = r * PK_STR + ks * 128 + g * 32;
                int s = (r & 7) << 4;
                uint4 p0 = *reinterpret_cast<const uint4*>(sm + OFF_RROW + (base ^ s));
                uint4 p1 = *reinterpret_cast<const uint4*>(sm + OFF_RROW + ((base + 16) ^ s));
                unpack2(p0, p1, ah[mt], al[mt]);
            }
            #pragma unroll
            for (int nt = 0; nt < 2; ++nt) {
                int n = 32 * wc + 16 * nt + q;
                int base = n * PK_STR + ks * 128 + g * 32;
                int s = (n & 7) << 4;
                uint4 p0 = *reinterpret_cast<const uint4*>(sm + OFF_RCOL + (base ^ s));
                uint4 p1 = *reinterpret_cast<const uint4*>(sm + OFF_RCOL + ((base + 16) ^ s));
                unpack2(p0, p1, bh[nt], bl[nt]);
            }
            #pragma unroll
            for (int mt = 0; mt < 2; ++mt)
                #pragma unroll
                for (int nt = 0; nt < 2; ++nt) {
                    acc[mt][nt] = __builtin_amdgcn_mfma_f32_16x16x32_bf16(ah[mt], bh[nt], acc[mt][nt], 0, 0, 0);
                    acc[mt][nt] = __builtin_amdgcn_mfma_f32_16x16x32_bf16(ah[mt], bl[nt], acc[mt][nt], 0, 0, 0);
                    acc[mt][nt] = __builtin_amdgcn_mfma_f32_16x16x32_bf16(al[mt], bh[nt], acc[mt][nt], 0, 0, 0);
                }
        }
    };

    f32x4 acc[2][2];

    // ---- mm1: A2 = A*A = -(A*A^T) ----
    acc[0][0] = zf; acc[0][1] = zf; acc[1][0] = zf; acc[1][1] = zf;
    mm_bf(OFF_A, OFF_A, acc);
    {
        u16* a2 = reinterpret_cast<u16*>(sm + OFF_A2);
        #pragma unroll
        for (int mt = 0; mt < 2; ++mt)
            #pragma unroll
            for (int nt = 0; nt < 2; ++nt)
                #pragma unroll
                for (int e = 0; e < 4; ++e) {
                    int r = 32 * wr + 16 * mt + 4 * g + e, c = 32 * wc + 16 * nt + q;
                    a2[r * 72 + c] = (u16)bf16_rne(-acc[mt][nt][e]);
                }
    }
    __syncthreads();

    // ---- mm2: A3 = A2*A = -(A2*A^T); P = I/6 + A/24 + A2/120 + A3/720 ----
    acc[0][0] = zf; acc[0][1] = zf; acc[1][0] = zf; acc[1][1] = zf;
    mm_bf(OFF_A2, OFF_A, acc);
    {
        u16* pa = reinterpret_cast<u16*>(sm + OFF_A);
        u16* a2 = reinterpret_cast<u16*>(sm + OFF_A2);
        u16* a3 = reinterpret_cast<u16*>(sm + OFF_A3);
        u16* pp = reinterpret_cast<u16*>(sm + OFF_P);
        #pragma unroll
        for (int mt = 0; mt < 2; ++mt)
            #pragma unroll
            for (int nt = 0; nt < 2; ++nt)
                #pragma unroll
                for (int e = 0; e < 4; ++e) {
                    int r = 32 * wr + 16 * mt + 4 * g + e, c = 32 * wc + 16 * nt + q;
                    float x3 = -acc[mt][nt][e];
                    a3[r * 72 + c] = (u16)bf16_rne(x3);
                    float af  = bf2f(pa[r * 72 + c]);
                    float a2f = bf2f(a2[r * 72 + c]);
                    float pv = ((r == c) ? (1.f / 6.f) : 0.f)
                             + af * (1.f / 24.f) + a2f * (1.f / 120.f) + x3 * (1.f / 720.f);
                    pp[r * 72 + c] = (u16)bf16_rne(pv);
                }
    }
    __syncthreads();

    // ---- mm3: M = P*A3 = -(P*A3^T); T6 = I + A + A2/2 + M -> R planes ----
    acc[0][0] = zf; acc[0][1] = zf; acc[1][0] = zf; acc[1][1] = zf;
    mm_bf(OFF_P, OFF_A3, acc);
    {
        u16* pa = reinterpret_cast<u16*>(sm + OFF_A);
        u16* a2 = reinterpret_cast<u16*>(sm + OFF_A2);
        u32 pk[2][2][4];
        #pragma unroll
        for (int mt = 0; mt < 2; ++mt)
            #pragma unroll
            for (int nt = 0; nt < 2; ++nt)
                #pragma unroll
                for (int e = 0; e < 4; ++e) {
                    int r = 32 * wr + 16 * mt + 4 * g + e, c = 32 * wc + 16 * nt + q;
                    float m = -acc[mt][nt][e];
                    float t6 = ((r == c) ? 1.f : 0.f)
                             + bf2f(pa[r * 72 + c]) + 0.5f * bf2f(a2[r * 72 + c]) + m;
                    pk[mt][nt][e] = pack_split(t6);
                }
        __syncthreads();   // all reads of A/A2/A3/P done before overwrite
        #pragma unroll
        for (int mt = 0; mt < 2; ++mt)
            #pragma unroll
            for (int nt = 0; nt < 2; ++nt) {
                #pragma unroll
                for (int e = 0; e < 4; ++e) {
                    int r = 32 * wr + 16 * mt + 4 * g + e, c = 32 * wc + 16 * nt + q;
                    *reinterpret_cast<u32*>(sm + OFF_RROW + ((r * PK_STR + c * 4) ^ ((r & 7) << 4))) = pk[mt][nt][e];
                }
                int n = 32 * wc + 16 * nt + q, r0 = 32 * wr + 16 * mt + 4 * g;
                uint4 v; v.x = pk[mt][nt][0]; v.y = pk[mt][nt][1]; v.z = pk[mt][nt][2]; v.w = pk[mt][nt][3];
                *reinterpret_cast<uint4*>(sm + OFF_RCOL + ((n * PK_STR + r0 * 4) ^ ((n & 7) << 4))) = v;
            }
    }
    __syncthreads();

    // ---- 4 in-place squarings ----
    #pragma unroll 1
    for (int sq = 0; sq < 4; ++sq) {
        acc[0][0] = zf; acc[0][1] = zf; acc[1][0] = zf; acc[1][1] = zf;
        mm_sq(acc);
        u32 pk[2][2][4];
        #pragma unroll
        for (int mt = 0; mt < 2; ++mt)
            #pragma unroll
            for (int nt = 0; nt < 2; ++nt)
                #pragma unroll
                for (int e = 0; e < 4; ++e)
                    pk[mt][nt][e] = pack_split(acc[mt][nt][e]);
        __syncthreads();   // all reads done before overwrite
        #pragma unroll
        for (int mt = 0; mt < 2; ++mt)
            #pragma unroll
            for (int nt = 0; nt < 2; ++nt) {
                #pragma unroll
                for (int e = 0; e < 4; ++e) {
                    int r = 32 * wr + 16 * mt + 4 * g + e, c = 32 * wc + 16 * nt + q;
                    *reinterpret_cast<u32*>(sm + OFF_RROW + ((r * PK_STR + c * 4) ^ ((r & 7) << 4))) = pk[mt][nt][e];
                }
                int n = 32 * wc + 16 * nt + q, r0 = 32 * wr + 16 * mt + 4 * g;
                uint4 v; v.x = pk[mt][nt][0]; v.y = pk[mt][nt][1]; v.z = pk[mt][nt][2]; v.w = pk[mt][nt][3];
                *reinterpret_cast<uint4*>(sm + OFF_RCOL + ((n * PK_STR + r0 * 4) ^ ((n & 7) << 4))) = v;
            }
        __syncthreads();
    }

    // ---- 5th squaring: straight to global ----
    acc[0][0] = zf; acc[0][1] = zf; acc[1][0] = zf; acc[1][1] = zf;
    mm_sq(acc);
    float* op = out + (size_t)b * 4096;
    #pragma unroll
    for (int mt = 0; mt < 2; ++mt)
        #pragma unroll
        for (int nt = 0; nt < 2; ++nt)
            #pragma unroll
            for (int e = 0; e < 4; ++e) {
                int r = 32 * wr + 16 * mt + 4 * g + e, c = 32 * wc + 16 * nt + q;
                op[r * 64 + c] = acc[mt][nt][e];
            }
    (void)nbatch;
}

extern "C" void kernel_launch(void* const* d_in, const int* in_sizes, int n_in,
                              void* d_out, int out_size, void* d_ws, size_t ws_size,
                              hipStream_t stream) {
    const float* theta = (const float*)d_in[0];
    float* out = (float*)d_out;
    const int nbatch = in_sizes[0] / NTH;   // 8192
    so_expm_mfma<<<nbatch, 256, 0, stream>>>(theta, out, nbatch);
}